// Round 1
// baseline (1518.651 us; speedup 1.0000x reference)
//
#include <hip/hip_runtime.h>
#include <stdint.h>

// WeightOnlyInt4Linear: y[b,s,n] = sum_k x[b,s,k] * ((q[n,k]-8)*s[k/G,n] + z[k/G,n])
// GEMM view: M=8192 (B*S), K=4096, N=11008, G=128.
// Strategy: bf16 MFMA (16x16x32), 128x128 tile, BK=32, fused dequant in staging.

typedef __attribute__((ext_vector_type(8))) short short8;
typedef __attribute__((ext_vector_type(4))) float float4v;
typedef __attribute__((ext_vector_type(4))) int int4v;
typedef __attribute__((ext_vector_type(2))) float float2v;
typedef __attribute__((ext_vector_type(4))) unsigned short ushort4v;

static constexpr int M_ = 8192;
static constexpr int K_ = 4096;
static constexpr int N_ = 11008;

static constexpr int BM = 128;
static constexpr int BN = 128;
static constexpr int BK = 32;
static constexpr int LDSS = 40;  // bf16 elems per LDS row: 32 + 8 pad (80 B -> step 20 banks, <=2-way)

__device__ inline unsigned short f2bf(float f) {
    union { float f; uint32_t u; } v;
    v.f = f;
    uint32_t u = v.u;
    u += 0x7fffu + ((u >> 16) & 1u);  // round-to-nearest-even
    return (unsigned short)(u >> 16);
}

__global__ __launch_bounds__(256, 2) void w4_gemm_fused(
    const float* __restrict__ X,   // [M][K] fp32
    const int* __restrict__ Q,     // [N][K] int32 codes 0..15
    const float* __restrict__ SZ,  // [K/G][N][2] fp32 (scale, zero)
    float* __restrict__ C)         // [M][N] fp32
{
    __shared__ alignas(16) unsigned short As[BM * LDSS];
    __shared__ alignas(16) unsigned short Ws[BN * LDSS];

    const int tid = threadIdx.x;
    const int lane = tid & 63;
    const int wid = tid >> 6;
    const int wr = wid >> 1;  // wave row (0..1)
    const int wc = wid & 1;   // wave col (0..1)

    const int row0 = blockIdx.x * BM;
    const int col0 = blockIdx.y * BN;

    float4v acc[4][4] = {};  // each wave: 64x64 output = 4x4 fragments of 16x16

    // Staging regs for one K-tile: 1024 float4/int4 chunks, 256 threads -> 4 each.
    // idx = tid + 256*i ; row-in-tile = idx>>3 ; vec4-in-row = idx&7  (32 elems/row)
    float4v a_reg[4];
    int4v   q_reg[4];
    float2v sz_reg[4];

    auto load_tile = [&](int kb) {
        const int g = kb >> 7;  // group index (G=128, BK=32 -> whole tile one group)
        #pragma unroll
        for (int i = 0; i < 4; ++i) {
            const int idx = tid + 256 * i;
            const int r = idx >> 3;
            const int v = idx & 7;
            a_reg[i]  = *(const float4v*)(X + (size_t)(row0 + r) * K_ + kb + v * 4);
            q_reg[i]  = *(const int4v*)(Q + (size_t)(col0 + r) * K_ + kb + v * 4);
            sz_reg[i] = *(const float2v*)(SZ + ((size_t)g * N_ + (col0 + r)) * 2);
        }
    };

    auto write_tile = [&]() {
        #pragma unroll
        for (int i = 0; i < 4; ++i) {
            const int idx = tid + 256 * i;
            const int r = idx >> 3;
            const int v = idx & 7;
            ushort4v ab, wb;
            #pragma unroll
            for (int j = 0; j < 4; ++j) ab[j] = f2bf(a_reg[i][j]);
            const float s = sz_reg[i][0];
            const float z = sz_reg[i][1];
            #pragma unroll
            for (int j = 0; j < 4; ++j)
                wb[j] = f2bf((float)(q_reg[i][j] - 8) * s + z);
            *(ushort4v*)(&As[r * LDSS + v * 4]) = ab;  // byte off = r*80 + v*8 (8B aligned)
            *(ushort4v*)(&Ws[r * LDSS + v * 4]) = wb;
        }
    };

    auto compute = [&]() {
        const int lr = lane & 15;
        const int lg = lane >> 4;  // 0..3, k-offset group
        short8 af[4], bf[4];
        #pragma unroll
        for (int mf = 0; mf < 4; ++mf)
            af[mf] = *(const short8*)(&As[(wr * 64 + mf * 16 + lr) * LDSS + lg * 8]);
        #pragma unroll
        for (int nf = 0; nf < 4; ++nf)
            bf[nf] = *(const short8*)(&Ws[(wc * 64 + nf * 16 + lr) * LDSS + lg * 8]);
        #pragma unroll
        for (int mf = 0; mf < 4; ++mf) {
            #pragma unroll
            for (int nf = 0; nf < 4; ++nf)
                acc[mf][nf] = __builtin_amdgcn_mfma_f32_16x16x32_bf16(
                    af[mf], bf[nf], acc[mf][nf], 0, 0, 0);
        }
    };

    load_tile(0);
    for (int kb = 0; kb < K_; kb += BK) {
        __syncthreads();  // previous compute's LDS reads done
        write_tile();
        __syncthreads();  // tile visible
        if (kb + BK < K_) load_tile(kb + BK);  // prefetch next tile under compute
        compute();
    }

    // Epilogue: D mapping col = lane&15, row = (lane>>4)*4 + j  (m89-verified)
    const int lr = lane & 15;
    const int lg = lane >> 4;
    #pragma unroll
    for (int mf = 0; mf < 4; ++mf) {
        #pragma unroll
        for (int nf = 0; nf < 4; ++nf) {
            #pragma unroll
            for (int j = 0; j < 4; ++j) {
                const int r = row0 + wr * 64 + mf * 16 + lg * 4 + j;
                const int c = col0 + wc * 64 + nf * 16 + lr;
                C[(size_t)r * N_ + c] = acc[mf][nf][j];
            }
        }
    }
}

extern "C" void kernel_launch(void* const* d_in, const int* in_sizes, int n_in,
                              void* d_out, int out_size, void* d_ws, size_t ws_size,
                              hipStream_t stream) {
    const float* X  = (const float*)d_in[0];  // x [4,2048,4096] fp32
    const int*   Q  = (const int*)d_in[1];    // weight_q [11008,4096] int32
    const float* SZ = (const float*)d_in[2];  // scales_and_zeros [32,11008,2] fp32
    float* C = (float*)d_out;                 // [4,2048,11008] fp32

    dim3 grid(M_ / BM, N_ / BN);  // 64 x 86, exact
    w4_gemm_fused<<<grid, dim3(256), 0, stream>>>(X, Q, SZ, C);
}

// Round 2
// 1294.278 us; speedup vs baseline: 1.1734x; 1.1734x over previous
//
#include <hip/hip_runtime.h>
#include <stdint.h>

// WeightOnlyInt4Linear: y = X @ dequant(Q)^T
// M=8192 (B*S), K=4096, N=11008, G=128.
// Round 2: prepass dequant/convert to bf16 in d_ws, then m97-structure bf16 GEMM
// (128x128 tile, BK=32, global_load_lds width-16, 2-barrier K-loop).

typedef __attribute__((ext_vector_type(8))) short short8;
typedef __attribute__((ext_vector_type(4))) float float4v;
typedef __attribute__((ext_vector_type(4))) int int4v;
typedef __attribute__((ext_vector_type(2))) float float2v;
typedef __attribute__((ext_vector_type(4))) unsigned short ushort4v;

static constexpr int M_ = 8192;
static constexpr int K_ = 4096;
static constexpr int N_ = 11008;

__device__ __forceinline__ unsigned short f2bf(float f) {
    union { float f; uint32_t u; } v;
    v.f = f;
    uint32_t u = v.u;
    u += 0x7fffu + ((u >> 16) & 1u);  // RNE
    return (unsigned short)(u >> 16);
}

__device__ __forceinline__ void gload_lds16(const void* g, void* l) {
    __builtin_amdgcn_global_load_lds(
        (const __attribute__((address_space(1))) uint32_t*)g,
        (__attribute__((address_space(3))) uint32_t*)l,
        16, 0, 0);
}

// ---------------- Prepass 1: X fp32 -> bf16 ----------------
__global__ __launch_bounds__(256) void cvt_x_kernel(const float* __restrict__ X,
                                                    unsigned short* __restrict__ Xb) {
    const int i = blockIdx.x * 256 + threadIdx.x;  // i < M*K/8
    const float4v a = ((const float4v*)X)[2 * (size_t)i];
    const float4v b = ((const float4v*)X)[2 * (size_t)i + 1];
    short8 o;
    #pragma unroll
    for (int j = 0; j < 4; ++j) o[j] = (short)f2bf(a[j]);
    #pragma unroll
    for (int j = 0; j < 4; ++j) o[4 + j] = (short)f2bf(b[j]);
    ((short8*)Xb)[(size_t)i] = o;
}

// ---------------- Prepass 2: W int4-codes -> bf16 (groupwise dequant) --------
__global__ __launch_bounds__(256) void deq_w_kernel(const int* __restrict__ Q,
                                                    const float* __restrict__ SZ,
                                                    unsigned short* __restrict__ Wb) {
    const int i = blockIdx.x * 256 + threadIdx.x;  // i < N*K/8 = 5,636,096
    const int n = i >> 9;        // K/8 = 512 chunks per row
    const int c = i & 511;
    const int k0 = c * 8;
    const int g = k0 >> 7;       // G = 128
    const float2v sz = *(const float2v*)(SZ + ((size_t)g * N_ + n) * 2);
    const float s = sz[0], z = sz[1];
    const int4v q0 = *(const int4v*)(Q + (size_t)n * K_ + k0);
    const int4v q1 = *(const int4v*)(Q + (size_t)n * K_ + k0 + 4);
    short8 o;
    #pragma unroll
    for (int j = 0; j < 4; ++j) o[j] = (short)f2bf((float)(q0[j] - 8) * s + z);
    #pragma unroll
    for (int j = 0; j < 4; ++j) o[4 + j] = (short)f2bf((float)(q1[j] - 8) * s + z);
    ((short8*)Wb)[(size_t)i] = o;
}

// ---------------- Main GEMM: m97 structure, bf16, 128x128, BK=32 -------------
__global__ __launch_bounds__(256) void gemm_bf16(const unsigned short* __restrict__ A,
                                                 const unsigned short* __restrict__ Wt,
                                                 float* __restrict__ C) {
    __shared__ alignas(16) unsigned short As[128 * 32];  // linear, no pad (gload_lds)
    __shared__ alignas(16) unsigned short Bs[128 * 32];

    const int tid = threadIdx.x;
    const int lane = tid & 63;
    const int wid = tid >> 6;
    const int wr = wid >> 1;
    const int wc = wid & 1;

    const int row0 = blockIdx.x * 128;
    const int col0 = blockIdx.y * 128;

    const int lr = lane & 15;
    const int lg = lane >> 4;
    const int srow = lane >> 2;        // 0..15 (row within 16-row segment)
    const int skoff = (lane & 3) * 8;  // bf16 offset within 32-elem row

    float4v acc[4][4] = {};

    for (int kb = 0; kb < K_; kb += 32) {
        // Stage A and B tiles: 8 segments of 16 rows each, 2 per wave per matrix.
        #pragma unroll
        for (int i = 0; i < 2; ++i) {
            const int seg = wid * 2 + i;  // 0..7
            const int row = seg * 16 + srow;
            gload_lds16(A + (size_t)(row0 + row) * K_ + kb + skoff, &As[seg * 512]);
            gload_lds16(Wt + (size_t)(col0 + row) * K_ + kb + skoff, &Bs[seg * 512]);
        }
        __syncthreads();  // vmcnt(0) drain + barrier: LDS tiles ready

        short8 af[4], bf[4];
        #pragma unroll
        for (int mf = 0; mf < 4; ++mf)
            af[mf] = *(const short8*)(&As[(wr * 64 + mf * 16 + lr) * 32 + lg * 8]);
        #pragma unroll
        for (int nf = 0; nf < 4; ++nf)
            bf[nf] = *(const short8*)(&Bs[(wc * 64 + nf * 16 + lr) * 32 + lg * 8]);
        #pragma unroll
        for (int mf = 0; mf < 4; ++mf)
            #pragma unroll
            for (int nf = 0; nf < 4; ++nf)
                acc[mf][nf] = __builtin_amdgcn_mfma_f32_16x16x32_bf16(
                    af[mf], bf[nf], acc[mf][nf], 0, 0, 0);
        __syncthreads();  // LDS reads done before next stage overwrites
    }

    // Epilogue: D mapping col = lane&15, row = (lane>>4)*4 + j (m89-verified)
    #pragma unroll
    for (int mf = 0; mf < 4; ++mf)
        #pragma unroll
        for (int nf = 0; nf < 4; ++nf)
            #pragma unroll
            for (int j = 0; j < 4; ++j) {
                const int r = row0 + wr * 64 + mf * 16 + lg * 4 + j;
                const int c = col0 + wc * 64 + nf * 16 + lr;
                C[(size_t)r * N_ + c] = acc[mf][nf][j];
            }
}

// ---------------- Fallback: round-1 fused kernel (if ws too small) -----------
static constexpr int LDSS = 40;

__global__ __launch_bounds__(256, 2) void w4_gemm_fused(
    const float* __restrict__ X, const int* __restrict__ Q,
    const float* __restrict__ SZ, float* __restrict__ C) {
    __shared__ alignas(16) unsigned short As[128 * LDSS];
    __shared__ alignas(16) unsigned short Ws[128 * LDSS];
    const int tid = threadIdx.x;
    const int lane = tid & 63;
    const int wid = tid >> 6;
    const int wr = wid >> 1;
    const int wc = wid & 1;
    const int row0 = blockIdx.x * 128;
    const int col0 = blockIdx.y * 128;
    float4v acc[4][4] = {};
    float4v a_reg[4];
    int4v q_reg[4];
    float2v sz_reg[4];

    auto load_tile = [&](int kb) {
        const int g = kb >> 7;
        #pragma unroll
        for (int i = 0; i < 4; ++i) {
            const int idx = tid + 256 * i;
            const int r = idx >> 3;
            const int v = idx & 7;
            a_reg[i] = *(const float4v*)(X + (size_t)(row0 + r) * K_ + kb + v * 4);
            q_reg[i] = *(const int4v*)(Q + (size_t)(col0 + r) * K_ + kb + v * 4);
            sz_reg[i] = *(const float2v*)(SZ + ((size_t)g * N_ + (col0 + r)) * 2);
        }
    };
    auto write_tile = [&]() {
        #pragma unroll
        for (int i = 0; i < 4; ++i) {
            const int idx = tid + 256 * i;
            const int r = idx >> 3;
            const int v = idx & 7;
            ushort4v ab, wb;
            #pragma unroll
            for (int j = 0; j < 4; ++j) ab[j] = f2bf(a_reg[i][j]);
            const float s = sz_reg[i][0];
            const float z = sz_reg[i][1];
            #pragma unroll
            for (int j = 0; j < 4; ++j) wb[j] = f2bf((float)(q_reg[i][j] - 8) * s + z);
            *(ushort4v*)(&As[r * LDSS + v * 4]) = ab;
            *(ushort4v*)(&Ws[r * LDSS + v * 4]) = wb;
        }
    };
    auto compute = [&]() {
        const int lr = lane & 15;
        const int lg = lane >> 4;
        short8 af[4], bf[4];
        #pragma unroll
        for (int mf = 0; mf < 4; ++mf)
            af[mf] = *(const short8*)(&As[(wr * 64 + mf * 16 + lr) * LDSS + lg * 8]);
        #pragma unroll
        for (int nf = 0; nf < 4; ++nf)
            bf[nf] = *(const short8*)(&Ws[(wc * 64 + nf * 16 + lr) * LDSS + lg * 8]);
        #pragma unroll
        for (int mf = 0; mf < 4; ++mf)
            #pragma unroll
            for (int nf = 0; nf < 4; ++nf)
                acc[mf][nf] = __builtin_amdgcn_mfma_f32_16x16x32_bf16(
                    af[mf], bf[nf], acc[mf][nf], 0, 0, 0);
    };

    load_tile(0);
    for (int kb = 0; kb < K_; kb += 32) {
        __syncthreads();
        write_tile();
        __syncthreads();
        if (kb + 32 < K_) load_tile(kb + 32);
        compute();
    }
    const int lr = lane & 15;
    const int lg = lane >> 4;
    #pragma unroll
    for (int mf = 0; mf < 4; ++mf)
        #pragma unroll
        for (int nf = 0; nf < 4; ++nf)
            #pragma unroll
            for (int j = 0; j < 4; ++j) {
                const int r = row0 + wr * 64 + mf * 16 + lg * 4 + j;
                const int c = col0 + wc * 64 + nf * 16 + lr;
                C[(size_t)r * N_ + c] = acc[mf][nf][j];
            }
}

extern "C" void kernel_launch(void* const* d_in, const int* in_sizes, int n_in,
                              void* d_out, int out_size, void* d_ws, size_t ws_size,
                              hipStream_t stream) {
    const float* X  = (const float*)d_in[0];   // [8192][4096] fp32
    const int*   Q  = (const int*)d_in[1];     // [11008][4096] int32 codes
    const float* SZ = (const float*)d_in[2];   // [32][11008][2] fp32
    float* C = (float*)d_out;                  // [8192][11008] fp32

    const size_t xb_bytes = (size_t)M_ * K_ * 2;            // 67,108,864
    const size_t wb_bytes = (size_t)N_ * K_ * 2;            // 90,177,536
    if (ws_size >= xb_bytes + wb_bytes) {
        unsigned short* Xb = (unsigned short*)d_ws;
        unsigned short* Wb = (unsigned short*)((char*)d_ws + xb_bytes);
        cvt_x_kernel<<<(M_ * (K_ / 8)) / 256, 256, 0, stream>>>(X, Xb);        // 16384 blocks
        deq_w_kernel<<<(N_ * (K_ / 8)) / 256, 256, 0, stream>>>(Q, SZ, Wb);    // 22016 blocks
        dim3 grid(M_ / 128, N_ / 128);  // 64 x 86
        gemm_bf16<<<grid, dim3(256), 0, stream>>>(Xb, Wb, C);
    } else {
        dim3 grid(M_ / 128, N_ / 128);
        w4_gemm_fused<<<grid, dim3(256), 0, stream>>>(X, Q, SZ, C);
    }
}

// Round 4
// 984.298 us; speedup vs baseline: 1.5429x; 1.3149x over previous
//
#include <hip/hip_runtime.h>
#include <stdint.h>

// WeightOnlyInt4Linear: y = X @ dequant(Q)^T ; M=8192, K=4096, N=11008, G=128.
// Round 4: prepass dequant to bf16 in d_ws + 256x256 8-phase GEMM.
// Fix vs round 3: fragment rows realigned so MH/NH == staged half-tiles
// (arow = MH*128 + wr*64 + ..., brow = NH*128 + wc*32 + ...) eliminating the
// P5 stage-into-live-region race.

typedef __attribute__((ext_vector_type(8))) short short8;
typedef __attribute__((ext_vector_type(4))) float float4v;
typedef __attribute__((ext_vector_type(4))) int int4v;
typedef __attribute__((ext_vector_type(2))) float float2v;
typedef __attribute__((ext_vector_type(4))) unsigned short ushort4v;

static constexpr int M_ = 8192;
static constexpr int K_ = 4096;
static constexpr int N_ = 11008;
static constexpr int NKT = K_ / 64;  // 64 K-tiles

__device__ __forceinline__ unsigned short f2bf(float f) {
    union { float f; uint32_t u; } v;
    v.f = f;
    uint32_t u = v.u;
    u += 0x7fffu + ((u >> 16) & 1u);  // RNE
    return (unsigned short)(u >> 16);
}

__device__ __forceinline__ void gload16(const void* g, void* l) {
    __builtin_amdgcn_global_load_lds(
        (const __attribute__((address_space(1))) uint32_t*)g,
        (__attribute__((address_space(3))) uint32_t*)l, 16, 0, 0);
}

// ---------------- Prepass 1: X fp32 -> bf16 ----------------
__global__ __launch_bounds__(256) void cvt_x_kernel(const float* __restrict__ X,
                                                    unsigned short* __restrict__ Xb) {
    const int i = blockIdx.x * 256 + threadIdx.x;
    const float4v a = ((const float4v*)X)[2 * (size_t)i];
    const float4v b = ((const float4v*)X)[2 * (size_t)i + 1];
    short8 o;
    #pragma unroll
    for (int j = 0; j < 4; ++j) o[j] = (short)f2bf(a[j]);
    #pragma unroll
    for (int j = 0; j < 4; ++j) o[4 + j] = (short)f2bf(b[j]);
    ((short8*)Xb)[(size_t)i] = o;
}

// ---------------- Prepass 2: W int4 codes -> bf16 ----------------
__global__ __launch_bounds__(256) void deq_w_kernel(const int* __restrict__ Q,
                                                    const float* __restrict__ SZ,
                                                    unsigned short* __restrict__ Wb) {
    const int i = blockIdx.x * 256 + threadIdx.x;  // < N*K/8
    const int n = i >> 9;
    const int c = i & 511;
    const int k0 = c * 8;
    const int g = k0 >> 7;
    const float2v sz = *(const float2v*)(SZ + ((size_t)g * N_ + n) * 2);
    const float s = sz[0], z = sz[1];
    const int4v q0 = *(const int4v*)(Q + (size_t)n * K_ + k0);
    const int4v q1 = *(const int4v*)(Q + (size_t)n * K_ + k0 + 4);
    short8 o;
    #pragma unroll
    for (int j = 0; j < 4; ++j) o[j] = (short)f2bf((float)(q0[j] - 8) * s + z);
    #pragma unroll
    for (int j = 0; j < 4; ++j) o[4 + j] = (short)f2bf((float)(q1[j] - 8) * s + z);
    ((short8*)Wb)[(size_t)i] = o;
}

// ---------------- 256x256 8-phase GEMM ----------------
// LDS (bytes): A buf0 [0,32K) A buf1 [32K,64K) B buf0 [64K,96K) B buf1 [96K,128K)
// Tile: 256 rows x 64 bf16 (128 B/row); half = 128 rows = 16 KB.
// Swizzle: phys_col_byte = logical_col_byte ^ ((row&4)<<4).

struct Frags { short8 a[4][2]; short8 b[2][2]; };

template <int BUF, int MH, int NH>
__device__ __forceinline__ void phase_reads(const char* ldsB, Frags& f,
                                            int aRB, int bRB, int k0o, int k1o) {
    // A row = MH*128 + wr*64 + i*16 + l15 ; B row = NH*128 + wc*32 + j*16 + l15
    const int abase = BUF * 32768 + MH * 16384 + aRB;
    const int bbase = 65536 + BUF * 32768 + NH * 16384 + bRB;
    #pragma unroll
    for (int i = 0; i < 4; ++i) {
        f.a[i][0] = *(const short8*)(ldsB + abase + i * 2048 + k0o);
        f.a[i][1] = *(const short8*)(ldsB + abase + i * 2048 + k1o);
    }
    #pragma unroll
    for (int j = 0; j < 2; ++j) {
        f.b[j][0] = *(const short8*)(ldsB + bbase + j * 2048 + k0o);
        f.b[j][1] = *(const short8*)(ldsB + bbase + j * 2048 + k1o);
    }
}

template <int MH, int NH>
__device__ __forceinline__ void phase_mma(Frags& f, float4v (&acc)[8][4]) {
    __builtin_amdgcn_s_setprio(1);
    #pragma unroll
    for (int i = 0; i < 4; ++i)
        #pragma unroll
        for (int j = 0; j < 2; ++j) {
            acc[MH * 4 + i][NH * 2 + j] = __builtin_amdgcn_mfma_f32_16x16x32_bf16(
                f.a[i][0], f.b[j][0], acc[MH * 4 + i][NH * 2 + j], 0, 0, 0);
            acc[MH * 4 + i][NH * 2 + j] = __builtin_amdgcn_mfma_f32_16x16x32_bf16(
                f.a[i][1], f.b[j][1], acc[MH * 4 + i][NH * 2 + j], 0, 0, 0);
        }
    __builtin_amdgcn_s_setprio(0);
}

#define BAR()                               \
    __builtin_amdgcn_s_barrier();           \
    __builtin_amdgcn_sched_barrier(0)
#define VMW(n) asm volatile("s_waitcnt vmcnt(" #n ")" ::: "memory")

__global__ __launch_bounds__(512, 2) void gemm_bf16_8ph(
    const unsigned short* __restrict__ Agl,  // [M][K] bf16
    const unsigned short* __restrict__ Bgl,  // [N][K] bf16
    float* __restrict__ C) {
    __shared__ alignas(16) unsigned short lds[65536];  // 128 KiB

    const int tid = threadIdx.x;
    const int lane = tid & 63;
    const int wid = tid >> 6;   // 0..7
    const int wr = wid >> 2;    // 0..1 (M sub-block within half)
    const int wc = wid & 3;     // 0..3 (N sub-block within half)

    // T1: XCD swizzle over 1376 = 8*172 blocks.
    const int bid = blockIdx.x;
    const int wg = (bid & 7) * 172 + (bid >> 3);
    const int mt = wg / 43;
    const int nt = wg % 43;
    const int row0 = mt * 256;
    const int col0 = nt * 256;

    // staging lane geometry
    const int r8 = lane >> 3;                    // 0..7
    const int kc = ((lane & 7) ^ (r8 & 4)) * 8;  // inverse-swizzled k-elem offset

    // ds_read lane geometry
    const int l15 = lane & 15;
    const int k0o = ((lane >> 4) * 16) ^ ((lane & 4) << 4);  // row bit2 = lane&4
    const int k1o = k0o ^ 64;
    const int aRB = (wr * 64 + l15) * 128;
    const int bRB = (wc * 32 + l15) * 128;
    const char* ldsB = (const char*)lds;
    unsigned short* ldsU = lds;

    auto stageA = [&](int kt, int b, int h) {
        #pragma unroll
        for (int i = 0; i < 2; ++i) {
            const int rbase = h * 128 + (wid * 2 + i) * 8;
            gload16(Agl + (size_t)(row0 + rbase + r8) * K_ + kt * 64 + kc,
                    ldsU + b * 16384 + rbase * 64);
        }
    };
    auto stageB = [&](int kt, int b, int h) {
        #pragma unroll
        for (int i = 0; i < 2; ++i) {
            const int rbase = h * 128 + (wid * 2 + i) * 8;
            gload16(Bgl + (size_t)(col0 + rbase + r8) * K_ + kt * 64 + kc,
                    ldsU + 32768 + b * 16384 + rbase * 64);
        }
    };

    float4v acc[8][4] = {};

    // Prologue: tile 0 (buf0) fully + A(1,h0) into buf1; leave A(1,h0) in flight.
    stageA(0, 0, 0); stageA(0, 0, 1); stageB(0, 0, 0); stageB(0, 0, 1);
    stageA(1, 1, 0);
    VMW(2);
    BAR();

    int t;
    // Phase read/consume map (with realigned rows):
    //  P1 <0,0>: A h0, B h0   P3 <0,1>: A h0, B h1
    //  P5 <1,0>: A h1, B h0   P7 <1,1>: A h1, B h1
    // Stage P5 writes A(t+2) h0 into BUF: h0 last read at P3. Safe.
#define KTILE(BUF)                                                        \
    {                                                                     \
        Frags f;                                                          \
        phase_reads<BUF, 0, 0>(ldsB, f, aRB, bRB, k0o, k1o);              \
        if (t + 1 < NKT) { stageA(t + 1, BUF ^ 1, 1); stageB(t + 1, BUF ^ 1, 0); } \
        BAR();                                                            \
        phase_mma<0, 0>(f, acc);                                          \
        BAR();                                                            \
        phase_reads<BUF, 0, 1>(ldsB, f, aRB, bRB, k0o, k1o);              \
        if (t + 1 < NKT) stageB(t + 1, BUF ^ 1, 1);                       \
        BAR();                                                            \
        phase_mma<0, 1>(f, acc);                                          \
        BAR();                                                            \
        phase_reads<BUF, 1, 0>(ldsB, f, aRB, bRB, k0o, k1o);              \
        if (t + 2 < NKT) stageA(t + 2, BUF, 0);                           \
        BAR();                                                            \
        phase_mma<1, 0>(f, acc);                                          \
        BAR();                                                            \
        phase_reads<BUF, 1, 1>(ldsB, f, aRB, bRB, k0o, k1o);              \
        BAR();                                                            \
        phase_mma<1, 1>(f, acc);                                          \
        if (t + 2 < NKT) { VMW(2); } else { VMW(0); }                     \
        BAR();                                                            \
    }

    for (int t2 = 0; t2 < NKT; t2 += 2) {
        t = t2;     KTILE(0);
        t = t2 + 1; KTILE(1);
    }
#undef KTILE

    // Epilogue: D map col=lane&15, row=(lane>>4)*4+j (m89-verified).
    // r = row0 + (mf>>2)*128 + wr*64 + (mf&3)*16 + (lane>>4)*4 + j
    // c = col0 + (nf>>1)*128 + wc*32 + (nf&1)*16 + l15
    const int lrow = (lane >> 4) * 4;
    #pragma unroll
    for (int mf = 0; mf < 8; ++mf)
        #pragma unroll
        for (int nf = 0; nf < 4; ++nf)
            #pragma unroll
            for (int j = 0; j < 4; ++j) {
                const int r = row0 + (mf >> 2) * 128 + wr * 64 + (mf & 3) * 16 + lrow + j;
                const int c = col0 + (nf >> 1) * 128 + wc * 32 + (nf & 1) * 16 + l15;
                C[(size_t)r * N_ + c] = acc[mf][nf][j];
            }
}

// ---------------- Fallback: round-1 fused kernel ----------------
static constexpr int LDSS = 40;

__global__ __launch_bounds__(256, 2) void w4_gemm_fused(
    const float* __restrict__ X, const int* __restrict__ Q,
    const float* __restrict__ SZ, float* __restrict__ C) {
    __shared__ alignas(16) unsigned short As[128 * LDSS];
    __shared__ alignas(16) unsigned short Ws[128 * LDSS];
    const int tid = threadIdx.x;
    const int lane = tid & 63;
    const int wid = tid >> 6;
    const int wrr = wid >> 1;
    const int wcc = wid & 1;
    const int row0 = blockIdx.x * 128;
    const int col0 = blockIdx.y * 128;
    float4v acc[4][4] = {};
    float4v a_reg[4];
    int4v q_reg[4];
    float2v sz_reg[4];

    auto load_tile = [&](int kb) {
        const int g = kb >> 7;
        #pragma unroll
        for (int i = 0; i < 4; ++i) {
            const int idx = tid + 256 * i;
            const int r = idx >> 3;
            const int v = idx & 7;
            a_reg[i] = *(const float4v*)(X + (size_t)(row0 + r) * K_ + kb + v * 4);
            q_reg[i] = *(const int4v*)(Q + (size_t)(col0 + r) * K_ + kb + v * 4);
            sz_reg[i] = *(const float2v*)(SZ + ((size_t)g * N_ + (col0 + r)) * 2);
        }
    };
    auto write_tile = [&]() {
        #pragma unroll
        for (int i = 0; i < 4; ++i) {
            const int idx = tid + 256 * i;
            const int r = idx >> 3;
            const int v = idx & 7;
            ushort4v ab, wb;
            #pragma unroll
            for (int j = 0; j < 4; ++j) ab[j] = f2bf(a_reg[i][j]);
            const float s = sz_reg[i][0];
            const float z = sz_reg[i][1];
            #pragma unroll
            for (int j = 0; j < 4; ++j) wb[j] = f2bf((float)(q_reg[i][j] - 8) * s + z);
            *(ushort4v*)(&As[r * LDSS + v * 4]) = ab;
            *(ushort4v*)(&Ws[r * LDSS + v * 4]) = wb;
        }
    };
    auto compute = [&]() {
        const int lr = lane & 15;
        const int lg = lane >> 4;
        short8 af[4], bf[4];
        #pragma unroll
        for (int mf = 0; mf < 4; ++mf)
            af[mf] = *(const short8*)(&As[(wrr * 64 + mf * 16 + lr) * LDSS + lg * 8]);
        #pragma unroll
        for (int nf = 0; nf < 4; ++nf)
            bf[nf] = *(const short8*)(&Ws[(wcc * 64 + nf * 16 + lr) * LDSS + lg * 8]);
        #pragma unroll
        for (int mf = 0; mf < 4; ++mf)
            #pragma unroll
            for (int nf = 0; nf < 4; ++nf)
                acc[mf][nf] = __builtin_amdgcn_mfma_f32_16x16x32_bf16(
                    af[mf], bf[nf], acc[mf][nf], 0, 0, 0);
    };

    load_tile(0);
    for (int kb = 0; kb < K_; kb += 32) {
        __syncthreads();
        write_tile();
        __syncthreads();
        if (kb + 32 < K_) load_tile(kb + 32);
        compute();
    }
    const int lr = lane & 15;
    const int lg = lane >> 4;
    #pragma unroll
    for (int mf = 0; mf < 4; ++mf)
        #pragma unroll
        for (int nf = 0; nf < 4; ++nf)
            #pragma unroll
            for (int j = 0; j < 4; ++j) {
                const int r = row0 + wrr * 64 + mf * 16 + lg * 4 + j;
                const int c = col0 + wcc * 64 + nf * 16 + lr;
                C[(size_t)r * N_ + c] = acc[mf][nf][j];
            }
}

extern "C" void kernel_launch(void* const* d_in, const int* in_sizes, int n_in,
                              void* d_out, int out_size, void* d_ws, size_t ws_size,
                              hipStream_t stream) {
    const float* X  = (const float*)d_in[0];
    const int*   Q  = (const int*)d_in[1];
    const float* SZ = (const float*)d_in[2];
    float* C = (float*)d_out;

    const size_t xb_bytes = (size_t)M_ * K_ * 2;
    const size_t wb_bytes = (size_t)N_ * K_ * 2;
    if (ws_size >= xb_bytes + wb_bytes) {
        unsigned short* Xb = (unsigned short*)d_ws;
        unsigned short* Wb = (unsigned short*)((char*)d_ws + xb_bytes);
        cvt_x_kernel<<<(M_ * (K_ / 8)) / 256, 256, 0, stream>>>(X, Xb);
        deq_w_kernel<<<(N_ * (K_ / 8)) / 256, 256, 0, stream>>>(Q, SZ, Wb);
        gemm_bf16_8ph<<<dim3(1376), dim3(512), 0, stream>>>(Xb, Wb, C);
    } else {
        dim3 grid(M_ / 128, N_ / 128);
        w4_gemm_fused<<<grid, dim3(256), 0, stream>>>(X, Q, SZ, C);
    }
}

// Round 5
// 868.160 us; speedup vs baseline: 1.7493x; 1.1338x over previous
//
#include <hip/hip_runtime.h>
#include <stdint.h>

// WeightOnlyInt4Linear: y = X @ dequant(Q)^T ; M=8192, K=4096, N=11008, G=128.
// Round 5: same 256x256 8-phase GEMM as round 4, with the T2 swizzle upgraded
// from 1-bit (row&4 -> byte bit6) to 3-bit (row&7 -> byte bits[6:4]).
// Read-side bank math: 16 rows/quarter-wave now spread over 8 16B-slots = 2
// dwords/bank (free, m136) instead of 2 slots = 8-way conflict.

typedef __attribute__((ext_vector_type(8))) short short8;
typedef __attribute__((ext_vector_type(4))) float float4v;
typedef __attribute__((ext_vector_type(4))) int int4v;
typedef __attribute__((ext_vector_type(2))) float float2v;
typedef __attribute__((ext_vector_type(4))) unsigned short ushort4v;

static constexpr int M_ = 8192;
static constexpr int K_ = 4096;
static constexpr int N_ = 11008;
static constexpr int NKT = K_ / 64;  // 64 K-tiles

__device__ __forceinline__ unsigned short f2bf(float f) {
    union { float f; uint32_t u; } v;
    v.f = f;
    uint32_t u = v.u;
    u += 0x7fffu + ((u >> 16) & 1u);  // RNE
    return (unsigned short)(u >> 16);
}

__device__ __forceinline__ void gload16(const void* g, void* l) {
    __builtin_amdgcn_global_load_lds(
        (const __attribute__((address_space(1))) uint32_t*)g,
        (__attribute__((address_space(3))) uint32_t*)l, 16, 0, 0);
}

// ---------------- Prepass 1: X fp32 -> bf16 ----------------
__global__ __launch_bounds__(256) void cvt_x_kernel(const float* __restrict__ X,
                                                    unsigned short* __restrict__ Xb) {
    const int i = blockIdx.x * 256 + threadIdx.x;
    const float4v a = ((const float4v*)X)[2 * (size_t)i];
    const float4v b = ((const float4v*)X)[2 * (size_t)i + 1];
    short8 o;
    #pragma unroll
    for (int j = 0; j < 4; ++j) o[j] = (short)f2bf(a[j]);
    #pragma unroll
    for (int j = 0; j < 4; ++j) o[4 + j] = (short)f2bf(b[j]);
    ((short8*)Xb)[(size_t)i] = o;
}

// ---------------- Prepass 2: W int4 codes -> bf16 ----------------
__global__ __launch_bounds__(256) void deq_w_kernel(const int* __restrict__ Q,
                                                    const float* __restrict__ SZ,
                                                    unsigned short* __restrict__ Wb) {
    const int i = blockIdx.x * 256 + threadIdx.x;  // < N*K/8
    const int n = i >> 9;
    const int c = i & 511;
    const int k0 = c * 8;
    const int g = k0 >> 7;
    const float2v sz = *(const float2v*)(SZ + ((size_t)g * N_ + n) * 2);
    const float s = sz[0], z = sz[1];
    const int4v q0 = *(const int4v*)(Q + (size_t)n * K_ + k0);
    const int4v q1 = *(const int4v*)(Q + (size_t)n * K_ + k0 + 4);
    short8 o;
    #pragma unroll
    for (int j = 0; j < 4; ++j) o[j] = (short)f2bf((float)(q0[j] - 8) * s + z);
    #pragma unroll
    for (int j = 0; j < 4; ++j) o[4 + j] = (short)f2bf((float)(q1[j] - 8) * s + z);
    ((short8*)Wb)[(size_t)i] = o;
}

// ---------------- 256x256 8-phase GEMM ----------------
// LDS (bytes): A buf0 [0,32K) A buf1 [32K,64K) B buf0 [64K,96K) B buf1 [96K,128K)
// Tile: 256 rows x 64 bf16 (128 B/row); half = 128 rows = 16 KB.
// Swizzle: phys_col_byte = logical_col_byte ^ ((row&7)<<4).

struct Frags { short8 a[4][2]; short8 b[2][2]; };

template <int BUF, int MH, int NH>
__device__ __forceinline__ void phase_reads(const char* ldsB, Frags& f,
                                            int aRB, int bRB, int k0o, int k1o) {
    // A row = MH*128 + wr*64 + i*16 + l15 ; B row = NH*128 + wc*32 + j*16 + l15
    const int abase = BUF * 32768 + MH * 16384 + aRB;
    const int bbase = 65536 + BUF * 32768 + NH * 16384 + bRB;
    #pragma unroll
    for (int i = 0; i < 4; ++i) {
        f.a[i][0] = *(const short8*)(ldsB + abase + i * 2048 + k0o);
        f.a[i][1] = *(const short8*)(ldsB + abase + i * 2048 + k1o);
    }
    #pragma unroll
    for (int j = 0; j < 2; ++j) {
        f.b[j][0] = *(const short8*)(ldsB + bbase + j * 2048 + k0o);
        f.b[j][1] = *(const short8*)(ldsB + bbase + j * 2048 + k1o);
    }
}

template <int MH, int NH>
__device__ __forceinline__ void phase_mma(Frags& f, float4v (&acc)[8][4]) {
    __builtin_amdgcn_s_setprio(1);
    #pragma unroll
    for (int i = 0; i < 4; ++i)
        #pragma unroll
        for (int j = 0; j < 2; ++j) {
            acc[MH * 4 + i][NH * 2 + j] = __builtin_amdgcn_mfma_f32_16x16x32_bf16(
                f.a[i][0], f.b[j][0], acc[MH * 4 + i][NH * 2 + j], 0, 0, 0);
            acc[MH * 4 + i][NH * 2 + j] = __builtin_amdgcn_mfma_f32_16x16x32_bf16(
                f.a[i][1], f.b[j][1], acc[MH * 4 + i][NH * 2 + j], 0, 0, 0);
        }
    __builtin_amdgcn_s_setprio(0);
}

#define BAR()                               \
    __builtin_amdgcn_s_barrier();           \
    __builtin_amdgcn_sched_barrier(0)
#define VMW(n) asm volatile("s_waitcnt vmcnt(" #n ")" ::: "memory")

__global__ __launch_bounds__(512, 2) void gemm_bf16_8ph(
    const unsigned short* __restrict__ Agl,  // [M][K] bf16
    const unsigned short* __restrict__ Bgl,  // [N][K] bf16
    float* __restrict__ C) {
    __shared__ alignas(16) unsigned short lds[65536];  // 128 KiB

    const int tid = threadIdx.x;
    const int lane = tid & 63;
    const int wid = tid >> 6;   // 0..7
    const int wr = wid >> 2;    // 0..1 (M sub-block within half)
    const int wc = wid & 3;     // 0..3 (N sub-block within half)

    // T1: XCD swizzle over 1376 = 8*172 blocks.
    const int bid = blockIdx.x;
    const int wg = (bid & 7) * 172 + (bid >> 3);
    const int mt = wg / 43;
    const int nt = wg % 43;
    const int row0 = mt * 256;
    const int col0 = nt * 256;

    // staging lane geometry: wave writes 8 rows x 128 B linear; lane's row&7 = lane>>3.
    const int r8 = lane >> 3;                // 0..7 == row&7
    const int kc = ((lane & 7) ^ r8) * 8;    // inverse-swizzled global k-elem offset

    // ds_read lane geometry: read row&7 = l15&7 (all other row terms are mult of 16).
    const int l15 = lane & 15;
    const int k0o = ((lane >> 4) * 16) ^ ((l15 & 7) << 4);
    const int k1o = k0o ^ 64;  // bit6 XOR commutes with the row XOR on bits[6:4]
    const int aRB = (wr * 64 + l15) * 128;
    const int bRB = (wc * 32 + l15) * 128;
    const char* ldsB = (const char*)lds;
    unsigned short* ldsU = lds;

    auto stageA = [&](int kt, int b, int h) {
        #pragma unroll
        for (int i = 0; i < 2; ++i) {
            const int rbase = h * 128 + (wid * 2 + i) * 8;
            gload16(Agl + (size_t)(row0 + rbase + r8) * K_ + kt * 64 + kc,
                    ldsU + b * 16384 + rbase * 64);
        }
    };
    auto stageB = [&](int kt, int b, int h) {
        #pragma unroll
        for (int i = 0; i < 2; ++i) {
            const int rbase = h * 128 + (wid * 2 + i) * 8;
            gload16(Bgl + (size_t)(col0 + rbase + r8) * K_ + kt * 64 + kc,
                    ldsU + 32768 + b * 16384 + rbase * 64);
        }
    };

    float4v acc[8][4] = {};

    // Prologue: tile 0 (buf0) fully + A(1,h0) into buf1; leave A(1,h0) in flight.
    stageA(0, 0, 0); stageA(0, 0, 1); stageB(0, 0, 0); stageB(0, 0, 1);
    stageA(1, 1, 0);
    VMW(2);
    BAR();

    int t;
    // Phase read/consume map: P1 <0,0>: A h0,B h0  P3 <0,1>: A h0,B h1
    //                         P5 <1,0>: A h1,B h0  P7 <1,1>: A h1,B h1
#define KTILE(BUF)                                                        \
    {                                                                     \
        Frags f;                                                          \
        phase_reads<BUF, 0, 0>(ldsB, f, aRB, bRB, k0o, k1o);              \
        if (t + 1 < NKT) { stageA(t + 1, BUF ^ 1, 1); stageB(t + 1, BUF ^ 1, 0); } \
        BAR();                                                            \
        phase_mma<0, 0>(f, acc);                                          \
        BAR();                                                            \
        phase_reads<BUF, 0, 1>(ldsB, f, aRB, bRB, k0o, k1o);              \
        if (t + 1 < NKT) stageB(t + 1, BUF ^ 1, 1);                       \
        BAR();                                                            \
        phase_mma<0, 1>(f, acc);                                          \
        BAR();                                                            \
        phase_reads<BUF, 1, 0>(ldsB, f, aRB, bRB, k0o, k1o);              \
        if (t + 2 < NKT) stageA(t + 2, BUF, 0);                           \
        BAR();                                                            \
        phase_mma<1, 0>(f, acc);                                          \
        BAR();                                                            \
        phase_reads<BUF, 1, 1>(ldsB, f, aRB, bRB, k0o, k1o);              \
        BAR();                                                            \
        phase_mma<1, 1>(f, acc);                                          \
        if (t + 2 < NKT) { VMW(2); } else { VMW(0); }                     \
        BAR();                                                            \
    }

    for (int t2 = 0; t2 < NKT; t2 += 2) {
        t = t2;     KTILE(0);
        t = t2 + 1; KTILE(1);
    }
#undef KTILE

    // Epilogue: D map col=lane&15, row=(lane>>4)*4+j (m89-verified).
    const int lrow = (lane >> 4) * 4;
    #pragma unroll
    for (int mf = 0; mf < 8; ++mf)
        #pragma unroll
        for (int nf = 0; nf < 4; ++nf)
            #pragma unroll
            for (int j = 0; j < 4; ++j) {
                const int r = row0 + (mf >> 2) * 128 + wr * 64 + (mf & 3) * 16 + lrow + j;
                const int c = col0 + (nf >> 1) * 128 + wc * 32 + (nf & 1) * 16 + l15;
                C[(size_t)r * N_ + c] = acc[mf][nf][j];
            }
}

// ---------------- Fallback: round-1 fused kernel ----------------
static constexpr int LDSS = 40;

__global__ __launch_bounds__(256, 2) void w4_gemm_fused(
    const float* __restrict__ X, const int* __restrict__ Q,
    const float* __restrict__ SZ, float* __restrict__ C) {
    __shared__ alignas(16) unsigned short As[128 * LDSS];
    __shared__ alignas(16) unsigned short Ws[128 * LDSS];
    const int tid = threadIdx.x;
    const int lane = tid & 63;
    const int wid = tid >> 6;
    const int wrr = wid >> 1;
    const int wcc = wid & 1;
    const int row0 = blockIdx.x * 128;
    const int col0 = blockIdx.y * 128;
    float4v acc[4][4] = {};
    float4v a_reg[4];
    int4v q_reg[4];
    float2v sz_reg[4];

    auto load_tile = [&](int kb) {
        const int g = kb >> 7;
        #pragma unroll
        for (int i = 0; i < 4; ++i) {
            const int idx = tid + 256 * i;
            const int r = idx >> 3;
            const int v = idx & 7;
            a_reg[i] = *(const float4v*)(X + (size_t)(row0 + r) * K_ + kb + v * 4);
            q_reg[i] = *(const int4v*)(Q + (size_t)(col0 + r) * K_ + kb + v * 4);
            sz_reg[i] = *(const float2v*)(SZ + ((size_t)g * N_ + (col0 + r)) * 2);
        }
    };
    auto write_tile = [&]() {
        #pragma unroll
        for (int i = 0; i < 4; ++i) {
            const int idx = tid + 256 * i;
            const int r = idx >> 3;
            const int v = idx & 7;
            ushort4v ab, wb;
            #pragma unroll
            for (int j = 0; j < 4; ++j) ab[j] = f2bf(a_reg[i][j]);
            const float s = sz_reg[i][0];
            const float z = sz_reg[i][1];
            #pragma unroll
            for (int j = 0; j < 4; ++j) wb[j] = f2bf((float)(q_reg[i][j] - 8) * s + z);
            *(ushort4v*)(&As[r * LDSS + v * 4]) = ab;
            *(ushort4v*)(&Ws[r * LDSS + v * 4]) = wb;
        }
    };
    auto compute = [&]() {
        const int lr = lane & 15;
        const int lg = lane >> 4;
        short8 af[4], bf[4];
        #pragma unroll
        for (int mf = 0; mf < 4; ++mf)
            af[mf] = *(const short8*)(&As[(wrr * 64 + mf * 16 + lr) * LDSS + lg * 8]);
        #pragma unroll
        for (int nf = 0; nf < 4; ++nf)
            bf[nf] = *(const short8*)(&Ws[(wcc * 64 + nf * 16 + lr) * LDSS + lg * 8]);
        #pragma unroll
        for (int mf = 0; mf < 4; ++mf)
            #pragma unroll
            for (int nf = 0; nf < 4; ++nf)
                acc[mf][nf] = __builtin_amdgcn_mfma_f32_16x16x32_bf16(
                    af[mf], bf[nf], acc[mf][nf], 0, 0, 0);
    };

    load_tile(0);
    for (int kb = 0; kb < K_; kb += 32) {
        __syncthreads();
        write_tile();
        __syncthreads();
        if (kb + 32 < K_) load_tile(kb + 32);
        compute();
    }
    const int lr = lane & 15;
    const int lg = lane >> 4;
    #pragma unroll
    for (int mf = 0; mf < 4; ++mf)
        #pragma unroll
        for (int nf = 0; nf < 4; ++nf)
            #pragma unroll
            for (int j = 0; j < 4; ++j) {
                const int r = row0 + wrr * 64 + mf * 16 + lg * 4 + j;
                const int c = col0 + wcc * 64 + nf * 16 + lr;
                C[(size_t)r * N_ + c] = acc[mf][nf][j];
            }
}

extern "C" void kernel_launch(void* const* d_in, const int* in_sizes, int n_in,
                              void* d_out, int out_size, void* d_ws, size_t ws_size,
                              hipStream_t stream) {
    const float* X  = (const float*)d_in[0];
    const int*   Q  = (const int*)d_in[1];
    const float* SZ = (const float*)d_in[2];
    float* C = (float*)d_out;

    const size_t xb_bytes = (size_t)M_ * K_ * 2;
    const size_t wb_bytes = (size_t)N_ * K_ * 2;
    if (ws_size >= xb_bytes + wb_bytes) {
        unsigned short* Xb = (unsigned short*)d_ws;
        unsigned short* Wb = (unsigned short*)((char*)d_ws + xb_bytes);
        cvt_x_kernel<<<(M_ * (K_ / 8)) / 256, 256, 0, stream>>>(X, Xb);
        deq_w_kernel<<<(N_ * (K_ / 8)) / 256, 256, 0, stream>>>(Q, SZ, Wb);
        gemm_bf16_8ph<<<dim3(1376), dim3(512), 0, stream>>>(Xb, Wb, C);
    } else {
        dim3 grid(M_ / 128, N_ / 128);
        w4_gemm_fused<<<grid, dim3(256), 0, stream>>>(X, Q, SZ, C);
    }
}

// Round 6
// 777.120 us; speedup vs baseline: 1.9542x; 1.1172x over previous
//
#include <hip/hip_runtime.h>
#include <stdint.h>

// WeightOnlyInt4Linear: y = X @ dequant(Q)^T ; M=8192, K=4096, N=11008, G=128.
// Round 6: 256x256 8-phase GEMM with cross-phase fragment reuse:
// per K-tile each LDS fragment is read exactly ONCE (24 ds_read_b128/wave vs 48).
// B (both halves) kept in regs the whole tile; A loaded per half.
// Phase P7 has no reads -> its barrier pair dropped (6 barriers/tile).

typedef __attribute__((ext_vector_type(8))) short short8;
typedef __attribute__((ext_vector_type(4))) float float4v;
typedef __attribute__((ext_vector_type(4))) int int4v;
typedef __attribute__((ext_vector_type(2))) float float2v;
typedef __attribute__((ext_vector_type(4))) unsigned short ushort4v;

static constexpr int M_ = 8192;
static constexpr int K_ = 4096;
static constexpr int N_ = 11008;
static constexpr int NKT = K_ / 64;  // 64 K-tiles

__device__ __forceinline__ unsigned short f2bf(float f) {
    union { float f; uint32_t u; } v;
    v.f = f;
    uint32_t u = v.u;
    u += 0x7fffu + ((u >> 16) & 1u);  // RNE
    return (unsigned short)(u >> 16);
}

__device__ __forceinline__ void gload16(const void* g, void* l) {
    __builtin_amdgcn_global_load_lds(
        (const __attribute__((address_space(1))) uint32_t*)g,
        (__attribute__((address_space(3))) uint32_t*)l, 16, 0, 0);
}

// ---------------- Prepass 1: X fp32 -> bf16 ----------------
__global__ __launch_bounds__(256) void cvt_x_kernel(const float* __restrict__ X,
                                                    unsigned short* __restrict__ Xb) {
    const int i = blockIdx.x * 256 + threadIdx.x;
    const float4v a = ((const float4v*)X)[2 * (size_t)i];
    const float4v b = ((const float4v*)X)[2 * (size_t)i + 1];
    short8 o;
    #pragma unroll
    for (int j = 0; j < 4; ++j) o[j] = (short)f2bf(a[j]);
    #pragma unroll
    for (int j = 0; j < 4; ++j) o[4 + j] = (short)f2bf(b[j]);
    ((short8*)Xb)[(size_t)i] = o;
}

// ---------------- Prepass 2: W int4 codes -> bf16 ----------------
__global__ __launch_bounds__(256) void deq_w_kernel(const int* __restrict__ Q,
                                                    const float* __restrict__ SZ,
                                                    unsigned short* __restrict__ Wb) {
    const int i = blockIdx.x * 256 + threadIdx.x;  // < N*K/8
    const int n = i >> 9;
    const int c = i & 511;
    const int k0 = c * 8;
    const int g = k0 >> 7;
    const float2v sz = *(const float2v*)(SZ + ((size_t)g * N_ + n) * 2);
    const float s = sz[0], z = sz[1];
    const int4v q0 = *(const int4v*)(Q + (size_t)n * K_ + k0);
    const int4v q1 = *(const int4v*)(Q + (size_t)n * K_ + k0 + 4);
    short8 o;
    #pragma unroll
    for (int j = 0; j < 4; ++j) o[j] = (short)f2bf((float)(q0[j] - 8) * s + z);
    #pragma unroll
    for (int j = 0; j < 4; ++j) o[4 + j] = (short)f2bf((float)(q1[j] - 8) * s + z);
    ((short8*)Wb)[(size_t)i] = o;
}

// ---------------- 256x256 8-phase GEMM ----------------
// LDS (bytes): A buf0 [0,32K) A buf1 [32K,64K) B buf0 [64K,96K) B buf1 [96K,128K)
// Tile: 256 rows x 64 bf16 (128 B/row); half = 128 rows = 16 KB.
// Swizzle: phys_col_byte = logical_col_byte ^ ((row&7)<<4).

struct Frags {
    short8 a[4][2];      // current A-half: [m-frag][k-slice]
    short8 b[2][2][2];   // BOTH B halves resident: [NH][n-frag][k-slice]
};

template <int BUF, int MH>
__device__ __forceinline__ void read_a(const char* ldsB, Frags& f,
                                       int aRB, int k0o, int k1o) {
    const int abase = BUF * 32768 + MH * 16384 + aRB;
    #pragma unroll
    for (int i = 0; i < 4; ++i) {
        f.a[i][0] = *(const short8*)(ldsB + abase + i * 2048 + k0o);
        f.a[i][1] = *(const short8*)(ldsB + abase + i * 2048 + k1o);
    }
}

template <int BUF, int NH>
__device__ __forceinline__ void read_b(const char* ldsB, Frags& f,
                                       int bRB, int k0o, int k1o) {
    const int bbase = 65536 + BUF * 32768 + NH * 16384 + bRB;
    #pragma unroll
    for (int j = 0; j < 2; ++j) {
        f.b[NH][j][0] = *(const short8*)(ldsB + bbase + j * 2048 + k0o);
        f.b[NH][j][1] = *(const short8*)(ldsB + bbase + j * 2048 + k1o);
    }
}

template <int MH, int NH>
__device__ __forceinline__ void phase_mma(Frags& f, float4v (&acc)[8][4]) {
    __builtin_amdgcn_s_setprio(1);
    #pragma unroll
    for (int i = 0; i < 4; ++i)
        #pragma unroll
        for (int j = 0; j < 2; ++j) {
            acc[MH * 4 + i][NH * 2 + j] = __builtin_amdgcn_mfma_f32_16x16x32_bf16(
                f.a[i][0], f.b[NH][j][0], acc[MH * 4 + i][NH * 2 + j], 0, 0, 0);
            acc[MH * 4 + i][NH * 2 + j] = __builtin_amdgcn_mfma_f32_16x16x32_bf16(
                f.a[i][1], f.b[NH][j][1], acc[MH * 4 + i][NH * 2 + j], 0, 0, 0);
        }
    __builtin_amdgcn_s_setprio(0);
}

#define BAR()                               \
    __builtin_amdgcn_s_barrier();           \
    __builtin_amdgcn_sched_barrier(0)
#define VMW(n) asm volatile("s_waitcnt vmcnt(" #n ")" ::: "memory")

__global__ __launch_bounds__(512, 2) void gemm_bf16_8ph(
    const unsigned short* __restrict__ Agl,  // [M][K] bf16
    const unsigned short* __restrict__ Bgl,  // [N][K] bf16
    float* __restrict__ C) {
    __shared__ alignas(16) unsigned short lds[65536];  // 128 KiB

    const int tid = threadIdx.x;
    const int lane = tid & 63;
    const int wid = tid >> 6;   // 0..7
    const int wr = wid >> 2;    // 0..1 (M sub-block within half)
    const int wc = wid & 3;     // 0..3 (N sub-block within half)

    // T1: XCD swizzle over 1376 = 8*172 blocks.
    const int bid = blockIdx.x;
    const int wg = (bid & 7) * 172 + (bid >> 3);
    const int mt = wg / 43;
    const int nt = wg % 43;
    const int row0 = mt * 256;
    const int col0 = nt * 256;

    // staging lane geometry: wave writes 8 rows x 128 B linear; lane's row&7 = lane>>3.
    const int r8 = lane >> 3;                // 0..7 == row&7
    const int kc = ((lane & 7) ^ r8) * 8;    // inverse-swizzled global k-elem offset

    // ds_read lane geometry: read row&7 = l15&7 (other row terms are mult of 16).
    const int l15 = lane & 15;
    const int k0o = ((lane >> 4) * 16) ^ ((l15 & 7) << 4);
    const int k1o = k0o ^ 64;  // bit6 XOR commutes with the row XOR on bits[6:4]
    const int aRB = (wr * 64 + l15) * 128;
    const int bRB = (wc * 32 + l15) * 128;
    const char* ldsB = (const char*)lds;
    unsigned short* ldsU = lds;

    auto stageA = [&](int kt, int b, int h) {
        #pragma unroll
        for (int i = 0; i < 2; ++i) {
            const int rbase = h * 128 + (wid * 2 + i) * 8;
            gload16(Agl + (size_t)(row0 + rbase + r8) * K_ + kt * 64 + kc,
                    ldsU + b * 16384 + rbase * 64);
        }
    };
    auto stageB = [&](int kt, int b, int h) {
        #pragma unroll
        for (int i = 0; i < 2; ++i) {
            const int rbase = h * 128 + (wid * 2 + i) * 8;
            gload16(Bgl + (size_t)(col0 + rbase + r8) * K_ + kt * 64 + kc,
                    ldsU + 32768 + b * 16384 + rbase * 64);
        }
    };

    float4v acc[8][4] = {};

    // Prologue: tile 0 (buf0) fully + A(1,h0) into buf1; leave A(1,h0) in flight.
    stageA(0, 0, 0); stageA(0, 0, 1); stageB(0, 0, 0); stageB(0, 0, 1);
    stageA(1, 1, 0);
    VMW(2);
    BAR();

    int t;
    // Reuse map: P1 loads A h0 + B h0 -> mma(0,0)
    //            P2 loads B h1        -> mma(0,1)  [A h0 reused]
    //            P3 loads A h1        -> mma(1,0)  [B h0 reused from regs]
    //            P4 (no reads)        -> mma(1,1)  [A h1, B h1 reused]
    // Stage safety: P3's stageA(t+2,BUF,h0) targets a region last read in P1,
    // consumed before P2's barrier -> two barriers of separation.
#define KTILE(BUF)                                                        \
    {                                                                     \
        Frags f;                                                          \
        read_a<BUF, 0>(ldsB, f, aRB, k0o, k1o);                           \
        read_b<BUF, 0>(ldsB, f, bRB, k0o, k1o);                           \
        if (t + 1 < NKT) { stageA(t + 1, BUF ^ 1, 1); stageB(t + 1, BUF ^ 1, 0); } \
        BAR();                                                            \
        phase_mma<0, 0>(f, acc);                                          \
        BAR();                                                            \
        read_b<BUF, 1>(ldsB, f, bRB, k0o, k1o);                           \
        if (t + 1 < NKT) stageB(t + 1, BUF ^ 1, 1);                       \
        BAR();                                                            \
        phase_mma<0, 1>(f, acc);                                          \
        BAR();                                                            \
        read_a<BUF, 1>(ldsB, f, aRB, k0o, k1o);                           \
        if (t + 2 < NKT) stageA(t + 2, BUF, 0);                           \
        BAR();                                                            \
        phase_mma<1, 0>(f, acc);                                          \
        phase_mma<1, 1>(f, acc);                                          \
        if (t + 2 < NKT) { VMW(2); } else { VMW(0); }                     \
        BAR();                                                            \
    }

    for (int t2 = 0; t2 < NKT; t2 += 2) {
        t = t2;     KTILE(0);
        t = t2 + 1; KTILE(1);
    }
#undef KTILE

    // Epilogue: D map col=lane&15, row=(lane>>4)*4+j (m89-verified).
    const int lrow = (lane >> 4) * 4;
    #pragma unroll
    for (int mf = 0; mf < 8; ++mf)
        #pragma unroll
        for (int nf = 0; nf < 4; ++nf)
            #pragma unroll
            for (int j = 0; j < 4; ++j) {
                const int r = row0 + (mf >> 2) * 128 + wr * 64 + (mf & 3) * 16 + lrow + j;
                const int c = col0 + (nf >> 1) * 128 + wc * 32 + (nf & 1) * 16 + l15;
                C[(size_t)r * N_ + c] = acc[mf][nf][j];
            }
}

// ---------------- Fallback: round-1 fused kernel ----------------
static constexpr int LDSS = 40;

__global__ __launch_bounds__(256, 2) void w4_gemm_fused(
    const float* __restrict__ X, const int* __restrict__ Q,
    const float* __restrict__ SZ, float* __restrict__ C) {
    __shared__ alignas(16) unsigned short As[128 * LDSS];
    __shared__ alignas(16) unsigned short Ws[128 * LDSS];
    const int tid = threadIdx.x;
    const int lane = tid & 63;
    const int wid = tid >> 6;
    const int wrr = wid >> 1;
    const int wcc = wid & 1;
    const int row0 = blockIdx.x * 128;
    const int col0 = blockIdx.y * 128;
    float4v acc[4][4] = {};
    float4v a_reg[4];
    int4v q_reg[4];
    float2v sz_reg[4];

    auto load_tile = [&](int kb) {
        const int g = kb >> 7;
        #pragma unroll
        for (int i = 0; i < 4; ++i) {
            const int idx = tid + 256 * i;
            const int r = idx >> 3;
            const int v = idx & 7;
            a_reg[i] = *(const float4v*)(X + (size_t)(row0 + r) * K_ + kb + v * 4);
            q_reg[i] = *(const int4v*)(Q + (size_t)(col0 + r) * K_ + kb + v * 4);
            sz_reg[i] = *(const float2v*)(SZ + ((size_t)g * N_ + (col0 + r)) * 2);
        }
    };
    auto write_tile = [&]() {
        #pragma unroll
        for (int i = 0; i < 4; ++i) {
            const int idx = tid + 256 * i;
            const int r = idx >> 3;
            const int v = idx & 7;
            ushort4v ab, wb;
            #pragma unroll
            for (int j = 0; j < 4; ++j) ab[j] = f2bf(a_reg[i][j]);
            const float s = sz_reg[i][0];
            const float z = sz_reg[i][1];
            #pragma unroll
            for (int j = 0; j < 4; ++j) wb[j] = f2bf((float)(q_reg[i][j] - 8) * s + z);
            *(ushort4v*)(&As[r * LDSS + v * 4]) = ab;
            *(ushort4v*)(&Ws[r * LDSS + v * 4]) = wb;
        }
    };
    auto compute = [&]() {
        const int lr = lane & 15;
        const int lg = lane >> 4;
        short8 af[4], bf[4];
        #pragma unroll
        for (int mf = 0; mf < 4; ++mf)
            af[mf] = *(const short8*)(&As[(wrr * 64 + mf * 16 + lr) * LDSS + lg * 8]);
        #pragma unroll
        for (int nf = 0; nf < 4; ++nf)
            bf[nf] = *(const short8*)(&Ws[(wcc * 64 + nf * 16 + lr) * LDSS + lg * 8]);
        #pragma unroll
        for (int mf = 0; mf < 4; ++mf)
            #pragma unroll
            for (int nf = 0; nf < 4; ++nf)
                acc[mf][nf] = __builtin_amdgcn_mfma_f32_16x16x32_bf16(
                    af[mf], bf[nf], acc[mf][nf], 0, 0, 0);
    };

    load_tile(0);
    for (int kb = 0; kb < K_; kb += 32) {
        __syncthreads();
        write_tile();
        __syncthreads();
        if (kb + 32 < K_) load_tile(kb + 32);
        compute();
    }
    const int lr = lane & 15;
    const int lg = lane >> 4;
    #pragma unroll
    for (int mf = 0; mf < 4; ++mf)
        #pragma unroll
        for (int nf = 0; nf < 4; ++nf)
            #pragma unroll
            for (int j = 0; j < 4; ++j) {
                const int r = row0 + wrr * 64 + mf * 16 + lg * 4 + j;
                const int c = col0 + wcc * 64 + nf * 16 + lr;
                C[(size_t)r * N_ + c] = acc[mf][nf][j];
            }
}

extern "C" void kernel_launch(void* const* d_in, const int* in_sizes, int n_in,
                              void* d_out, int out_size, void* d_ws, size_t ws_size,
                              hipStream_t stream) {
    const float* X  = (const float*)d_in[0];
    const int*   Q  = (const int*)d_in[1];
    const float* SZ = (const float*)d_in[2];
    float* C = (float*)d_out;

    const size_t xb_bytes = (size_t)M_ * K_ * 2;
    const size_t wb_bytes = (size_t)N_ * K_ * 2;
    if (ws_size >= xb_bytes + wb_bytes) {
        unsigned short* Xb = (unsigned short*)d_ws;
        unsigned short* Wb = (unsigned short*)((char*)d_ws + xb_bytes);
        cvt_x_kernel<<<(M_ * (K_ / 8)) / 256, 256, 0, stream>>>(X, Xb);
        deq_w_kernel<<<(N_ * (K_ / 8)) / 256, 256, 0, stream>>>(Q, SZ, Wb);
        gemm_bf16_8ph<<<dim3(1376), dim3(512), 0, stream>>>(Xb, Wb, C);
    } else {
        dim3 grid(M_ / 128, N_ / 128);
        w4_gemm_fused<<<grid, dim3(256), 0, stream>>>(X, Q, SZ, C);
    }
}

// Round 7
// 744.591 us; speedup vs baseline: 2.0396x; 1.0437x over previous
//
#include <hip/hip_runtime.h>
#include <stdint.h>

// WeightOnlyInt4Linear: y = X @ dequant(Q)^T ; M=8192, K=4096, N=11008, G=128.
// Round 7: round-6 reuse schedule with barriers cut 6 -> 2 per K-tile.
// Only real intra-tile hazard: stageA(t+2,BUF,h0) vs P1 reads of A h0 -> one
// mid-tile barrier. All other staging targets BUF^1. End-of-tile VMW(2)+BAR
// keeps the counted-vmcnt ring. Compiler free to overlap ds_read & MFMA pipes.

typedef __attribute__((ext_vector_type(8))) short short8;
typedef __attribute__((ext_vector_type(4))) float float4v;
typedef __attribute__((ext_vector_type(4))) int int4v;
typedef __attribute__((ext_vector_type(2))) float float2v;
typedef __attribute__((ext_vector_type(4))) unsigned short ushort4v;

static constexpr int M_ = 8192;
static constexpr int K_ = 4096;
static constexpr int N_ = 11008;
static constexpr int NKT = K_ / 64;  // 64 K-tiles

__device__ __forceinline__ unsigned short f2bf(float f) {
    union { float f; uint32_t u; } v;
    v.f = f;
    uint32_t u = v.u;
    u += 0x7fffu + ((u >> 16) & 1u);  // RNE
    return (unsigned short)(u >> 16);
}

__device__ __forceinline__ void gload16(const void* g, void* l) {
    __builtin_amdgcn_global_load_lds(
        (const __attribute__((address_space(1))) uint32_t*)g,
        (__attribute__((address_space(3))) uint32_t*)l, 16, 0, 0);
}

// ---------------- Prepass 1: X fp32 -> bf16 ----------------
__global__ __launch_bounds__(256) void cvt_x_kernel(const float* __restrict__ X,
                                                    unsigned short* __restrict__ Xb) {
    const int i = blockIdx.x * 256 + threadIdx.x;
    const float4v a = ((const float4v*)X)[2 * (size_t)i];
    const float4v b = ((const float4v*)X)[2 * (size_t)i + 1];
    short8 o;
    #pragma unroll
    for (int j = 0; j < 4; ++j) o[j] = (short)f2bf(a[j]);
    #pragma unroll
    for (int j = 0; j < 4; ++j) o[4 + j] = (short)f2bf(b[j]);
    ((short8*)Xb)[(size_t)i] = o;
}

// ---------------- Prepass 2: W int4 codes -> bf16 ----------------
__global__ __launch_bounds__(256) void deq_w_kernel(const int* __restrict__ Q,
                                                    const float* __restrict__ SZ,
                                                    unsigned short* __restrict__ Wb) {
    const int i = blockIdx.x * 256 + threadIdx.x;  // < N*K/8
    const int n = i >> 9;
    const int c = i & 511;
    const int k0 = c * 8;
    const int g = k0 >> 7;
    const float2v sz = *(const float2v*)(SZ + ((size_t)g * N_ + n) * 2);
    const float s = sz[0], z = sz[1];
    const int4v q0 = *(const int4v*)(Q + (size_t)n * K_ + k0);
    const int4v q1 = *(const int4v*)(Q + (size_t)n * K_ + k0 + 4);
    short8 o;
    #pragma unroll
    for (int j = 0; j < 4; ++j) o[j] = (short)f2bf((float)(q0[j] - 8) * s + z);
    #pragma unroll
    for (int j = 0; j < 4; ++j) o[4 + j] = (short)f2bf((float)(q1[j] - 8) * s + z);
    ((short8*)Wb)[(size_t)i] = o;
}

// ---------------- 256x256 GEMM, 2 barriers/K-tile ----------------
// LDS (bytes): A buf0 [0,32K) A buf1 [32K,64K) B buf0 [64K,96K) B buf1 [96K,128K)
// Tile: 256 rows x 64 bf16 (128 B/row); half = 128 rows = 16 KB.
// Swizzle: phys_col_byte = logical_col_byte ^ ((row&7)<<4).

struct Frags {
    short8 a[4][2];      // current A-half: [m-frag][k-slice]
    short8 b[2][2][2];   // BOTH B halves resident: [NH][n-frag][k-slice]
};

template <int BUF, int MH>
__device__ __forceinline__ void read_a(const char* ldsB, Frags& f,
                                       int aRB, int k0o, int k1o) {
    const int abase = BUF * 32768 + MH * 16384 + aRB;
    #pragma unroll
    for (int i = 0; i < 4; ++i) {
        f.a[i][0] = *(const short8*)(ldsB + abase + i * 2048 + k0o);
        f.a[i][1] = *(const short8*)(ldsB + abase + i * 2048 + k1o);
    }
}

template <int BUF, int NH>
__device__ __forceinline__ void read_b(const char* ldsB, Frags& f,
                                       int bRB, int k0o, int k1o) {
    const int bbase = 65536 + BUF * 32768 + NH * 16384 + bRB;
    #pragma unroll
    for (int j = 0; j < 2; ++j) {
        f.b[NH][j][0] = *(const short8*)(ldsB + bbase + j * 2048 + k0o);
        f.b[NH][j][1] = *(const short8*)(ldsB + bbase + j * 2048 + k1o);
    }
}

template <int MH, int NH>
__device__ __forceinline__ void phase_mma(Frags& f, float4v (&acc)[8][4]) {
    __builtin_amdgcn_s_setprio(1);
    #pragma unroll
    for (int i = 0; i < 4; ++i)
        #pragma unroll
        for (int j = 0; j < 2; ++j) {
            acc[MH * 4 + i][NH * 2 + j] = __builtin_amdgcn_mfma_f32_16x16x32_bf16(
                f.a[i][0], f.b[NH][j][0], acc[MH * 4 + i][NH * 2 + j], 0, 0, 0);
            acc[MH * 4 + i][NH * 2 + j] = __builtin_amdgcn_mfma_f32_16x16x32_bf16(
                f.a[i][1], f.b[NH][j][1], acc[MH * 4 + i][NH * 2 + j], 0, 0, 0);
        }
    __builtin_amdgcn_s_setprio(0);
}

#define SBAR() __builtin_amdgcn_sched_barrier(0)
#define VMW(n) asm volatile("s_waitcnt vmcnt(" #n ")" ::: "memory")

__global__ __launch_bounds__(512, 2) void gemm_bf16_8ph(
    const unsigned short* __restrict__ Agl,  // [M][K] bf16
    const unsigned short* __restrict__ Bgl,  // [N][K] bf16
    float* __restrict__ C) {
    __shared__ alignas(16) unsigned short lds[65536];  // 128 KiB

    const int tid = threadIdx.x;
    const int lane = tid & 63;
    const int wid = tid >> 6;   // 0..7
    const int wr = wid >> 2;    // 0..1 (M sub-block within half)
    const int wc = wid & 3;     // 0..3 (N sub-block within half)

    // T1: XCD swizzle over 1376 = 8*172 blocks.
    const int bid = blockIdx.x;
    const int wg = (bid & 7) * 172 + (bid >> 3);
    const int mt = wg / 43;
    const int nt = wg % 43;
    const int row0 = mt * 256;
    const int col0 = nt * 256;

    // staging lane geometry: wave writes 8 rows x 128 B linear; lane's row&7 = lane>>3.
    const int r8 = lane >> 3;                // 0..7 == row&7
    const int kc = ((lane & 7) ^ r8) * 8;    // inverse-swizzled global k-elem offset

    // ds_read lane geometry: read row&7 = l15&7 (other row terms are mult of 16).
    const int l15 = lane & 15;
    const int k0o = ((lane >> 4) * 16) ^ ((l15 & 7) << 4);
    const int k1o = k0o ^ 64;  // bit6 XOR commutes with the row XOR on bits[6:4]
    const int aRB = (wr * 64 + l15) * 128;
    const int bRB = (wc * 32 + l15) * 128;
    const char* ldsB = (const char*)lds;
    unsigned short* ldsU = lds;

    auto stageA = [&](int kt, int b, int h) {
        #pragma unroll
        for (int i = 0; i < 2; ++i) {
            const int rbase = h * 128 + (wid * 2 + i) * 8;
            gload16(Agl + (size_t)(row0 + rbase + r8) * K_ + kt * 64 + kc,
                    ldsU + b * 16384 + rbase * 64);
        }
    };
    auto stageB = [&](int kt, int b, int h) {
        #pragma unroll
        for (int i = 0; i < 2; ++i) {
            const int rbase = h * 128 + (wid * 2 + i) * 8;
            gload16(Bgl + (size_t)(col0 + rbase + r8) * K_ + kt * 64 + kc,
                    ldsU + 32768 + b * 16384 + rbase * 64);
        }
    };

    float4v acc[8][4] = {};

    // Prologue: tile 0 (buf0) fully + A(1,h0) into buf1; leave A(1,h0) in flight.
    stageA(0, 0, 0); stageA(0, 0, 1); stageB(0, 0, 0); stageB(0, 0, 1);
    stageA(1, 1, 0);
    VMW(2);
    __builtin_amdgcn_s_barrier();
    SBAR();

    int t;
    // Hazard analysis (tile t, buffer BUF):
    //   writes this tile: A(t+1)h1, B(t+1)h0, B(t+1)h1 -> BUF^1 (not read here);
    //                     A(t+2)h0 -> BUF A h0 (read only by P1) -> mid barrier.
    //   A h1 / B h0 / B h1 of BUF are never written this tile -> reads float freely.
#define KTILE(BUF)                                                        \
    {                                                                     \
        Frags f;                                                          \
        read_a<BUF, 0>(ldsB, f, aRB, k0o, k1o);                           \
        read_b<BUF, 0>(ldsB, f, bRB, k0o, k1o);                           \
        if (t + 1 < NKT) { stageA(t + 1, BUF ^ 1, 1); stageB(t + 1, BUF ^ 1, 0); } \
        phase_mma<0, 0>(f, acc);                                          \
        read_b<BUF, 1>(ldsB, f, bRB, k0o, k1o);                           \
        if (t + 1 < NKT) stageB(t + 1, BUF ^ 1, 1);                       \
        phase_mma<0, 1>(f, acc);                                          \
        SBAR();                                                           \
        __builtin_amdgcn_s_barrier();  /* all waves past A-h0 reads */    \
        SBAR();                                                           \
        if (t + 2 < NKT) stageA(t + 2, BUF, 0);                           \
        read_a<BUF, 1>(ldsB, f, aRB, k0o, k1o);                           \
        phase_mma<1, 0>(f, acc);                                          \
        phase_mma<1, 1>(f, acc);                                          \
        SBAR();                                                           \
        if (t + 2 < NKT) { VMW(2); } else { VMW(0); }                     \
        __builtin_amdgcn_s_barrier();  /* next tile's data visible */     \
        SBAR();                                                           \
    }

    for (int t2 = 0; t2 < NKT; t2 += 2) {
        t = t2;     KTILE(0);
        t = t2 + 1; KTILE(1);
    }
#undef KTILE

    // Epilogue: D map col=lane&15, row=(lane>>4)*4+j (m89-verified).
    const int lrow = (lane >> 4) * 4;
    #pragma unroll
    for (int mf = 0; mf < 8; ++mf)
        #pragma unroll
        for (int nf = 0; nf < 4; ++nf)
            #pragma unroll
            for (int j = 0; j < 4; ++j) {
                const int r = row0 + (mf >> 2) * 128 + wr * 64 + (mf & 3) * 16 + lrow + j;
                const int c = col0 + (nf >> 1) * 128 + wc * 32 + (nf & 1) * 16 + l15;
                C[(size_t)r * N_ + c] = acc[mf][nf][j];
            }
}

// ---------------- Fallback: round-1 fused kernel ----------------
static constexpr int LDSS = 40;

__global__ __launch_bounds__(256, 2) void w4_gemm_fused(
    const float* __restrict__ X, const int* __restrict__ Q,
    const float* __restrict__ SZ, float* __restrict__ C) {
    __shared__ alignas(16) unsigned short As[128 * LDSS];
    __shared__ alignas(16) unsigned short Ws[128 * LDSS];
    const int tid = threadIdx.x;
    const int lane = tid & 63;
    const int wid = tid >> 6;
    const int wrr = wid >> 1;
    const int wcc = wid & 1;
    const int row0 = blockIdx.x * 128;
    const int col0 = blockIdx.y * 128;
    float4v acc[4][4] = {};
    float4v a_reg[4];
    int4v q_reg[4];
    float2v sz_reg[4];

    auto load_tile = [&](int kb) {
        const int g = kb >> 7;
        #pragma unroll
        for (int i = 0; i < 4; ++i) {
            const int idx = tid + 256 * i;
            const int r = idx >> 3;
            const int v = idx & 7;
            a_reg[i] = *(const float4v*)(X + (size_t)(row0 + r) * K_ + kb + v * 4);
            q_reg[i] = *(const int4v*)(Q + (size_t)(col0 + r) * K_ + kb + v * 4);
            sz_reg[i] = *(const float2v*)(SZ + ((size_t)g * N_ + (col0 + r)) * 2);
        }
    };
    auto write_tile = [&]() {
        #pragma unroll
        for (int i = 0; i < 4; ++i) {
            const int idx = tid + 256 * i;
            const int r = idx >> 3;
            const int v = idx & 7;
            ushort4v ab, wb;
            #pragma unroll
            for (int j = 0; j < 4; ++j) ab[j] = f2bf(a_reg[i][j]);
            const float s = sz_reg[i][0];
            const float z = sz_reg[i][1];
            #pragma unroll
            for (int j = 0; j < 4; ++j) wb[j] = f2bf((float)(q_reg[i][j] - 8) * s + z);
            *(ushort4v*)(&As[r * LDSS + v * 4]) = ab;
            *(ushort4v*)(&Ws[r * LDSS + v * 4]) = wb;
        }
    };
    auto compute = [&]() {
        const int lr = lane & 15;
        const int lg = lane >> 4;
        short8 af[4], bf[4];
        #pragma unroll
        for (int mf = 0; mf < 4; ++mf)
            af[mf] = *(const short8*)(&As[(wrr * 64 + mf * 16 + lr) * LDSS + lg * 8]);
        #pragma unroll
        for (int nf = 0; nf < 4; ++nf)
            bf[nf] = *(const short8*)(&Ws[(wcc * 64 + nf * 16 + lr) * LDSS + lg * 8]);
        #pragma unroll
        for (int mf = 0; mf < 4; ++mf)
            #pragma unroll
            for (int nf = 0; nf < 4; ++nf)
                acc[mf][nf] = __builtin_amdgcn_mfma_f32_16x16x32_bf16(
                    af[mf], bf[nf], acc[mf][nf], 0, 0, 0);
    };

    load_tile(0);
    for (int kb = 0; kb < K_; kb += 32) {
        __syncthreads();
        write_tile();
        __syncthreads();
        if (kb + 32 < K_) load_tile(kb + 32);
        compute();
    }
    const int lr = lane & 15;
    const int lg = lane >> 4;
    #pragma unroll
    for (int mf = 0; mf < 4; ++mf)
        #pragma unroll
        for (int nf = 0; nf < 4; ++nf)
            #pragma unroll
            for (int j = 0; j < 4; ++j) {
                const int r = row0 + wrr * 64 + mf * 16 + lg * 4 + j;
                const int c = col0 + wcc * 64 + nf * 16 + lr;
                C[(size_t)r * N_ + c] = acc[mf][nf][j];
            }
}

extern "C" void kernel_launch(void* const* d_in, const int* in_sizes, int n_in,
                              void* d_out, int out_size, void* d_ws, size_t ws_size,
                              hipStream_t stream) {
    const float* X  = (const float*)d_in[0];
    const int*   Q  = (const int*)d_in[1];
    const float* SZ = (const float*)d_in[2];
    float* C = (float*)d_out;

    const size_t xb_bytes = (size_t)M_ * K_ * 2;
    const size_t wb_bytes = (size_t)N_ * K_ * 2;
    if (ws_size >= xb_bytes + wb_bytes) {
        unsigned short* Xb = (unsigned short*)d_ws;
        unsigned short* Wb = (unsigned short*)((char*)d_ws + xb_bytes);
        cvt_x_kernel<<<(M_ * (K_ / 8)) / 256, 256, 0, stream>>>(X, Xb);
        deq_w_kernel<<<(N_ * (K_ / 8)) / 256, 256, 0, stream>>>(Q, SZ, Wb);
        gemm_bf16_8ph<<<dim3(1376), dim3(512), 0, stream>>>(Xb, Wb, C);
    } else {
        dim3 grid(M_ / 128, N_ / 128);
        w4_gemm_fused<<<grid, dim3(256), 0, stream>>>(X, Q, SZ, C);
    }
}